// Round 1
// baseline (265.659 us; speedup 1.0000x reference)
//
#include <hip/hip_runtime.h>
#include <stdint.h>

// Problem constants
#define S_LEN 2048
#define EMBED 1024
#define HEADS 16
#define HD 64
#define M_ROWS 4096      // B*S
#define N_QKV 3072
#define KDIM 1024
#define SP 2336          // padded vT row length: 128 + 2048 + 160

typedef __attribute__((ext_vector_type(8))) short short8;
typedef __attribute__((ext_vector_type(4))) float f32x4;

__device__ __forceinline__ unsigned short f2bf(float f) {
  union { float f; uint32_t u; } c; c.f = f;
  uint32_t u = c.u;
  u += 0x7fffu + ((u >> 16) & 1u);  // round-to-nearest-even
  return (unsigned short)(u >> 16);
}

// ---------------- fp32 -> bf16 conversion, 4 elems/thread ----------------
__global__ void cvt_kernel(const float* __restrict__ src, unsigned short* __restrict__ dst, int n4) {
  int i = blockIdx.x * blockDim.x + threadIdx.x;
  if (i >= n4) return;
  float4 f = reinterpret_cast<const float4*>(src)[i];
  ushort4 o;
  o.x = f2bf(f.x); o.y = f2bf(f.y); o.z = f2bf(f.z); o.w = f2bf(f.w);
  reinterpret_cast<ushort4*>(dst)[i] = o;
}

// ---------------- QKV projection GEMM: 64x64 tile, 4 waves, BK=32 ----------------
// A = xb [4096][1024] bf16, B = Wqkvb [3072][1024] bf16 (row n holds W[n][k] -> B[k][n] frag reads
// 8 contiguous k). Epilogue: +bias, padding-mask zero, scatter to q/k/vT(padded).
__global__ __launch_bounds__(256) void gemm_qkv(
    const unsigned short* __restrict__ A, const unsigned short* __restrict__ Bm,
    const float* __restrict__ bias, const int* __restrict__ pm,
    unsigned short* __restrict__ qo, unsigned short* __restrict__ ko,
    unsigned short* __restrict__ vTp)
{
  __shared__ __align__(16) unsigned short As[64][40];   // +8 pad: 2-way banks only
  __shared__ __align__(16) unsigned short Bs[64][40];
  const int nb = blockIdx.x, mb = blockIdx.y;
  const int t = threadIdx.x;
  const int r = t >> 2, c8 = (t & 3) << 3;
  const int wave = t >> 6, lane = t & 63;
  const int m16 = lane & 15, q4 = lane >> 4;
  const unsigned short* pA = A + (size_t)(mb * 64 + r) * KDIM + c8;
  const unsigned short* pB = Bm + (size_t)(nb * 64 + r) * KDIM + c8;
  f32x4 acc[4] = {{0.f,0.f,0.f,0.f},{0.f,0.f,0.f,0.f},{0.f,0.f,0.f,0.f},{0.f,0.f,0.f,0.f}};
  for (int kt = 0; kt < KDIM; kt += 32) {
    __syncthreads();
    *reinterpret_cast<int4*>(&As[r][c8]) = *reinterpret_cast<const int4*>(pA + kt);
    *reinterpret_cast<int4*>(&Bs[r][c8]) = *reinterpret_cast<const int4*>(pB + kt);
    __syncthreads();
    short8 a = *reinterpret_cast<const short8*>(&As[wave * 16 + m16][q4 * 8]);
#pragma unroll
    for (int nt = 0; nt < 4; nt++) {
      short8 b = *reinterpret_cast<const short8*>(&Bs[nt * 16 + m16][q4 * 8]);
      acc[nt] = __builtin_amdgcn_mfma_f32_16x16x32_bf16(a, b, acc[nt], 0, 0, 0);
    }
  }
  const int row0 = mb * 64 + wave * 16 + q4 * 4;
#pragma unroll
  for (int nt = 0; nt < 4; nt++) {
    int col = nb * 64 + nt * 16 + m16;      // qkv channel
    int h = col / 192, o = col % 192;
    float bv = bias[col];
#pragma unroll
    for (int reg = 0; reg < 4; reg++) {
      int row = row0 + reg;                 // bs index
      float v = acc[nt][reg] + bv;
      if (pm[row] != 0) v = 0.0f;
      unsigned short val = f2bf(v);
      int b = row >> 11, s = row & 2047;
      int bh = b * 16 + h;
      if (o < 64)       qo[((size_t)(bh * 2048 + s)) * 64 + o] = val;
      else if (o < 128) ko[((size_t)(bh * 2048 + s)) * 64 + (o - 64)] = val;
      else              vTp[((size_t)(bh * 64 + (o - 128))) * SP + 128 + s] = val;
    }
  }
}

// ---------------- banded attention: 1 wave / 16-query tile ----------------
__global__ __launch_bounds__(64) void attn_kernel(
    const unsigned short* __restrict__ q, const unsigned short* __restrict__ k,
    const unsigned short* __restrict__ vTp, unsigned short* __restrict__ vals)
{
  __shared__ __align__(16) float Sld[16][292];          // 292: conflict-free softmax
  __shared__ __align__(16) unsigned short Pld[16][296]; // 296: keeps 16B row alignment
  __shared__ float rden[16];
  const int qt = blockIdx.x, bh = blockIdx.y;
  const int i0 = qt * 16, w0 = i0 - 128;
  const int lane = threadIdx.x, m16 = lane & 15, q4 = lane >> 4;

  const unsigned short* qb = q + ((size_t)(bh * 2048 + i0 + m16)) * 64 + q4 * 8;
  short8 aq0 = *reinterpret_cast<const short8*>(qb);
  short8 aq1 = *reinterpret_cast<const short8*>(qb + 32);

  for (int ct = 0; ct < 18; ct++) {
    int js = w0 + ct * 16 + m16;                        // key index for this lane's column
    int jc = js < 0 ? 0 : (js > 2047 ? 2047 : js);
    const unsigned short* kb = k + ((size_t)(bh * 2048 + jc)) * 64 + q4 * 8;
    short8 b0 = *reinterpret_cast<const short8*>(kb);
    short8 b1 = *reinterpret_cast<const short8*>(kb + 32);
    f32x4 acc = {0.f, 0.f, 0.f, 0.f};
    acc = __builtin_amdgcn_mfma_f32_16x16x32_bf16(aq0, b0, acc, 0, 0, 0);
    acc = __builtin_amdgcn_mfma_f32_16x16x32_bf16(aq1, b1, acc, 0, 0, 0);
#pragma unroll
    for (int reg = 0; reg < 4; reg++) {
      int rowq = q4 * 4 + reg;
      int i = i0 + rowq;
      bool valid = (js >= 0) && (js < 2048) && (js >= i - 128) && (js <= i + 128);
      Sld[rowq][ct * 16 + m16] = valid ? acc[reg] * 0.125f : -1e30f;
    }
  }
  __syncthreads();
  {
    int rr = lane >> 2, p = lane & 3;                   // 4 lanes per query row
    float mx = -1e30f;
    for (int jj = p; jj < 288; jj += 4) mx = fmaxf(mx, Sld[rr][jj]);
    mx = fmaxf(mx, __shfl_xor(mx, 1));
    mx = fmaxf(mx, __shfl_xor(mx, 2));
    float sum = 0.f;
    for (int jj = p; jj < 288; jj += 4) {
      float e = __expf(Sld[rr][jj] - mx);
      sum += e;
      Pld[rr][jj] = f2bf(e);
    }
    sum += __shfl_xor(sum, 1);
    sum += __shfl_xor(sum, 2);
    if (p == 0) rden[rr] = 1.0f / sum;
  }
  __syncthreads();
  const int b = bh >> 4, h = bh & 15;
#pragma unroll
  for (int dt = 0; dt < 4; dt++) {
    f32x4 av = {0.f, 0.f, 0.f, 0.f};
    const unsigned short* vb = vTp + ((size_t)(bh * 64 + dt * 16 + m16)) * SP + i0 + q4 * 8; // 128+w0 = i0
    for (int kc = 0; kc < 9; kc++) {
      short8 ap = *reinterpret_cast<const short8*>(&Pld[m16][kc * 32 + q4 * 8]);
      short8 bv = *reinterpret_cast<const short8*>(vb + kc * 32);
      av = __builtin_amdgcn_mfma_f32_16x16x32_bf16(ap, bv, av, 0, 0, 0);
    }
#pragma unroll
    for (int reg = 0; reg < 4; reg++) {
      int rowq = q4 * 4 + reg;
      float val = av[reg] * rden[rowq];
      int s = i0 + rowq;
      int e = h * 64 + dt * 16 + m16;
      vals[((size_t)(b * 2048 + s)) * 1024 + e] = f2bf(val);
    }
  }
}

// ---------------- output projection GEMM (fp32 out + bias) ----------------
__global__ __launch_bounds__(256) void gemm_out(
    const unsigned short* __restrict__ A, const unsigned short* __restrict__ Bm,
    const float* __restrict__ bias, float* __restrict__ out)
{
  __shared__ __align__(16) unsigned short As[64][40];
  __shared__ __align__(16) unsigned short Bs[64][40];
  const int nb = blockIdx.x, mb = blockIdx.y;
  const int t = threadIdx.x;
  const int r = t >> 2, c8 = (t & 3) << 3;
  const int wave = t >> 6, lane = t & 63;
  const int m16 = lane & 15, q4 = lane >> 4;
  const unsigned short* pA = A + (size_t)(mb * 64 + r) * KDIM + c8;
  const unsigned short* pB = Bm + (size_t)(nb * 64 + r) * KDIM + c8;
  f32x4 acc[4] = {{0.f,0.f,0.f,0.f},{0.f,0.f,0.f,0.f},{0.f,0.f,0.f,0.f},{0.f,0.f,0.f,0.f}};
  for (int kt = 0; kt < KDIM; kt += 32) {
    __syncthreads();
    *reinterpret_cast<int4*>(&As[r][c8]) = *reinterpret_cast<const int4*>(pA + kt);
    *reinterpret_cast<int4*>(&Bs[r][c8]) = *reinterpret_cast<const int4*>(pB + kt);
    __syncthreads();
    short8 a = *reinterpret_cast<const short8*>(&As[wave * 16 + m16][q4 * 8]);
#pragma unroll
    for (int nt = 0; nt < 4; nt++) {
      short8 b = *reinterpret_cast<const short8*>(&Bs[nt * 16 + m16][q4 * 8]);
      acc[nt] = __builtin_amdgcn_mfma_f32_16x16x32_bf16(a, b, acc[nt], 0, 0, 0);
    }
  }
  const int row0 = mb * 64 + wave * 16 + q4 * 4;
#pragma unroll
  for (int nt = 0; nt < 4; nt++) {
    int col = nb * 64 + nt * 16 + m16;
    float bv = bias[col];
#pragma unroll
    for (int reg = 0; reg < 4; reg++) {
      int row = row0 + reg;
      out[(size_t)row * EMBED + col] = acc[nt][reg] + bv;
    }
  }
}

extern "C" void kernel_launch(void* const* d_in, const int* in_sizes, int n_in,
                              void* d_out, int out_size, void* d_ws, size_t ws_size,
                              hipStream_t stream) {
  const float* x    = (const float*)d_in[0];
  const int*   pm   = (const int*)d_in[1];
  const float* Wqkv = (const float*)d_in[2];
  const float* bqkv = (const float*)d_in[3];
  const float* Wo   = (const float*)d_in[4];
  const float* bo   = (const float*)d_in[5];
  float* out = (float*)d_out;
  char* ws = (char*)d_ws;

  // workspace layout (bytes); vals aliases xb (xb dead after gemm_qkv)
  unsigned short* xb    = (unsigned short*)(ws);                 //  8,388,608
  unsigned short* vals  = (unsigned short*)(ws);                 //  reuse
  unsigned short* Wqkvb = (unsigned short*)(ws +  8388608);      //  6,291,456
  unsigned short* Wob   = (unsigned short*)(ws + 14680064);      //  2,097,152
  unsigned short* qbuf  = (unsigned short*)(ws + 16777216);      //  8,388,608
  unsigned short* kbuf  = (unsigned short*)(ws + 25165824);      //  8,388,608
  unsigned short* vTp   = (unsigned short*)(ws + 33554432);      //  9,568,256 (ends 43,122,688)

  hipMemsetAsync(vTp, 0, (size_t)32 * 64 * SP * 2, stream);      // zero padded vT
  cvt_kernel<<<4096, 256, 0, stream>>>(x, xb, 1048576);
  cvt_kernel<<<3072, 256, 0, stream>>>(Wqkv, Wqkvb, 786432);
  cvt_kernel<<<1024, 256, 0, stream>>>(Wo, Wob, 262144);
  gemm_qkv<<<dim3(48, 64), 256, 0, stream>>>(xb, Wqkvb, bqkv, pm, qbuf, kbuf, vTp);
  attn_kernel<<<dim3(128, 32), 64, 0, stream>>>(qbuf, kbuf, vTp, vals);
  gemm_out<<<dim3(16, 64), 256, 0, stream>>>(vals, Wob, bo, out);
}

// Round 2
// 218.135 us; speedup vs baseline: 1.2179x; 1.2179x over previous
//
#include <hip/hip_runtime.h>
#include <stdint.h>

#define S_LEN 2048
#define EMBED 1024
#define HEADS 16
#define HD 64
#define M_ROWS 4096      // B*S
#define N_QKV 3072
#define KDIM 1024
#define SP 2336          // padded vT row length: 128 + 2048 + 160

typedef __attribute__((ext_vector_type(8))) short short8;
typedef __attribute__((ext_vector_type(4))) float f32x4;

__device__ __forceinline__ unsigned short f2bf(float f) {
  union { float f; uint32_t u; } c; c.f = f;
  uint32_t u = c.u;
  u += 0x7fffu + ((u >> 16) & 1u);  // round-to-nearest-even
  return (unsigned short)(u >> 16);
}

// async global->LDS, 16B per lane; lds base must be wave-uniform (HW adds lane*16)
__device__ __forceinline__ void gload_lds16(const unsigned short* g, unsigned short* l) {
  __builtin_amdgcn_global_load_lds(
      (const __attribute__((address_space(1))) void*)g,
      (__attribute__((address_space(3))) void*)l, 16, 0, 0);
}

// ---------------- fp32 -> bf16 conversion, 4 elems/thread ----------------
__global__ void cvt_kernel(const float* __restrict__ src, unsigned short* __restrict__ dst, int n4) {
  int i = blockIdx.x * blockDim.x + threadIdx.x;
  if (i >= n4) return;
  float4 f = reinterpret_cast<const float4*>(src)[i];
  ushort4 o;
  o.x = f2bf(f.x); o.y = f2bf(f.y); o.z = f2bf(f.z); o.w = f2bf(f.w);
  reinterpret_cast<ushort4*>(dst)[i] = o;
}

// ---------------- m97-style 128x128 GEMM bodies ----------------
// A[M][1024], B[N][1024] bf16 row-major (B row n = output col n, contiguous k).
// 4 waves in 2x2, each wave 64x64 via 4x4 grid of 16x16x32 MFMA, BK=32,
// staging via global_load_lds width 16 (LDS layout [row][32k] unpadded -- required).
#define GEMM128_BODY(A_, B_)                                                          \
  __shared__ __align__(16) unsigned short As[128 * 32];                               \
  __shared__ __align__(16) unsigned short Bs[128 * 32];                               \
  const int t = threadIdx.x, wave = t >> 6, lane = t & 63;                            \
  const int m16 = lane & 15, q4 = lane >> 4;                                          \
  const int wm = wave >> 1, wn = wave & 1;                                            \
  const int nb = blockIdx.x, mb = blockIdx.y;                                         \
  const int srow = lane >> 2, scol = (lane & 3) << 3;                                 \
  const unsigned short* pA0 = A_ + (size_t)(mb * 128 + (wave * 2 + 0) * 16 + srow) * KDIM + scol; \
  const unsigned short* pA1 = A_ + (size_t)(mb * 128 + (wave * 2 + 1) * 16 + srow) * KDIM + scol; \
  const unsigned short* pB0 = B_ + (size_t)(nb * 128 + (wave * 2 + 0) * 16 + srow) * KDIM + scol; \
  const unsigned short* pB1 = B_ + (size_t)(nb * 128 + (wave * 2 + 1) * 16 + srow) * KDIM + scol; \
  unsigned short* lA0 = &As[(wave * 2 + 0) * 512];                                    \
  unsigned short* lA1 = &As[(wave * 2 + 1) * 512];                                    \
  unsigned short* lB0 = &Bs[(wave * 2 + 0) * 512];                                    \
  unsigned short* lB1 = &Bs[(wave * 2 + 1) * 512];                                    \
  f32x4 acc[4][4];                                                                    \
  _Pragma("unroll") for (int i_ = 0; i_ < 4; i_++)                                    \
    _Pragma("unroll") for (int j_ = 0; j_ < 4; j_++)                                  \
      acc[i_][j_] = (f32x4){0.f, 0.f, 0.f, 0.f};                                      \
  for (int kt = 0; kt < KDIM; kt += 32) {                                             \
    __syncthreads();                                                                  \
    gload_lds16(pA0 + kt, lA0);                                                       \
    gload_lds16(pA1 + kt, lA1);                                                       \
    gload_lds16(pB0 + kt, lB0);                                                       \
    gload_lds16(pB1 + kt, lB1);                                                       \
    __syncthreads();                                                                  \
    short8 af[4], bf[4];                                                              \
    _Pragma("unroll") for (int mt = 0; mt < 4; mt++)                                  \
      af[mt] = *reinterpret_cast<const short8*>(&As[(wm * 64 + mt * 16 + m16) * 32 + q4 * 8]); \
    _Pragma("unroll") for (int nt = 0; nt < 4; nt++)                                  \
      bf[nt] = *reinterpret_cast<const short8*>(&Bs[(wn * 64 + nt * 16 + m16) * 32 + q4 * 8]); \
    _Pragma("unroll") for (int mt = 0; mt < 4; mt++)                                  \
      _Pragma("unroll") for (int nt = 0; nt < 4; nt++)                                \
        acc[mt][nt] = __builtin_amdgcn_mfma_f32_16x16x32_bf16(af[mt], bf[nt], acc[mt][nt], 0, 0, 0); \
  }

// QKV projection + bias + padding mask + scatter to q/k/vT(padded)
__global__ __launch_bounds__(256) void gemm_qkv(
    const unsigned short* __restrict__ A, const unsigned short* __restrict__ Bm,
    const float* __restrict__ bias, const int* __restrict__ pm,
    unsigned short* __restrict__ qo, unsigned short* __restrict__ ko,
    unsigned short* __restrict__ vTp)
{
  GEMM128_BODY(A, Bm)
#pragma unroll
  for (int nt = 0; nt < 4; nt++) {
    int col = nb * 128 + wn * 64 + nt * 16 + m16;
    int h = col / 192, o = col % 192;
    float bv = bias[col];
#pragma unroll
    for (int mt = 0; mt < 4; mt++) {
#pragma unroll
      for (int reg = 0; reg < 4; reg++) {
        int row = mb * 128 + wm * 64 + mt * 16 + q4 * 4 + reg;
        float v = acc[mt][nt][reg] + bv;
        if (pm[row] != 0) v = 0.0f;
        unsigned short val = f2bf(v);
        int b = row >> 11, s = row & 2047;
        int bh = b * 16 + h;
        if (o < 64)       qo[((size_t)(bh * 2048 + s)) * 64 + o] = val;
        else if (o < 128) ko[((size_t)(bh * 2048 + s)) * 64 + (o - 64)] = val;
        else              vTp[((size_t)(bh * 64 + (o - 128))) * SP + 128 + s] = val;
      }
    }
  }
}

// output projection (fp32 out + bias)
__global__ __launch_bounds__(256) void gemm_out(
    const unsigned short* __restrict__ A, const unsigned short* __restrict__ Bm,
    const float* __restrict__ bias, float* __restrict__ out)
{
  GEMM128_BODY(A, Bm)
#pragma unroll
  for (int nt = 0; nt < 4; nt++) {
    int col = nb * 128 + wn * 64 + nt * 16 + m16;
    float bv = bias[col];
#pragma unroll
    for (int mt = 0; mt < 4; mt++) {
#pragma unroll
      for (int reg = 0; reg < 4; reg++) {
        int row = mb * 128 + wm * 64 + mt * 16 + q4 * 4 + reg;
        out[(size_t)row * EMBED + col] = acc[mt][nt][reg] + bv;
      }
    }
  }
}

// ---------------- banded attention: 1 wave / 16-query tile, register softmax ----------------
__global__ __launch_bounds__(64) void attn_kernel(
    const unsigned short* __restrict__ q, const unsigned short* __restrict__ k,
    const unsigned short* __restrict__ vTp, unsigned short* __restrict__ vals)
{
  __shared__ __align__(16) unsigned short Pld[16][296]; // +8 pad keeps 16B align, 2-way banks
  const int qt = blockIdx.x, bh = blockIdx.y;
  const int i0 = qt * 16, w0 = i0 - 128;
  const int lane = threadIdx.x, m16 = lane & 15, q4 = lane >> 4;

  const unsigned short* qb = q + ((size_t)(bh * 2048 + i0 + m16)) * 64 + q4 * 8;
  short8 aq0 = *reinterpret_cast<const short8*>(qb);
  short8 aq1 = *reinterpret_cast<const short8*>(qb + 32);

  // QK^T: 18 column tiles of 16 keys, accumulators stay in registers
  f32x4 sc[18];
#pragma unroll
  for (int ct = 0; ct < 18; ct++) {
    int js = w0 + ct * 16 + m16;
    int jc = js < 0 ? 0 : (js > 2047 ? 2047 : js);
    const unsigned short* kb = k + ((size_t)(bh * 2048 + jc)) * 64 + q4 * 8;
    short8 b0 = *reinterpret_cast<const short8*>(kb);
    short8 b1 = *reinterpret_cast<const short8*>(kb + 32);
    f32x4 a = {0.f, 0.f, 0.f, 0.f};
    a = __builtin_amdgcn_mfma_f32_16x16x32_bf16(aq0, b0, a, 0, 0, 0);
    a = __builtin_amdgcn_mfma_f32_16x16x32_bf16(aq1, b1, a, 0, 0, 0);
    sc[ct] = a;
  }
  // mask + scale in registers; per-row max over {18 regs} x {16 m16-lanes}
  float mx[4] = {-3.0e38f, -3.0e38f, -3.0e38f, -3.0e38f};
#pragma unroll
  for (int ct = 0; ct < 18; ct++) {
    int js = w0 + ct * 16 + m16;
#pragma unroll
    for (int reg = 0; reg < 4; reg++) {
      int i = i0 + q4 * 4 + reg;
      bool valid = (js >= 0) && (js < 2048) && (js >= i - 128) && (js <= i + 128);
      float v = valid ? sc[ct][reg] * 0.125f : -3.0e38f;
      sc[ct][reg] = v;
      mx[reg] = fmaxf(mx[reg], v);
    }
  }
#pragma unroll
  for (int reg = 0; reg < 4; reg++) {
    mx[reg] = fmaxf(mx[reg], __shfl_xor(mx[reg], 1));
    mx[reg] = fmaxf(mx[reg], __shfl_xor(mx[reg], 2));
    mx[reg] = fmaxf(mx[reg], __shfl_xor(mx[reg], 4));
    mx[reg] = fmaxf(mx[reg], __shfl_xor(mx[reg], 8));
  }
  float sum[4] = {0.f, 0.f, 0.f, 0.f};
#pragma unroll
  for (int ct = 0; ct < 18; ct++) {
#pragma unroll
    for (int reg = 0; reg < 4; reg++) {
      float e = __expf(sc[ct][reg] - mx[reg]);  // masked -> exp(-huge) = 0
      sum[reg] += e;
      Pld[q4 * 4 + reg][ct * 16 + m16] = f2bf(e);
    }
  }
  float rden[4];
#pragma unroll
  for (int reg = 0; reg < 4; reg++) {
    float s = sum[reg];
    s += __shfl_xor(s, 1);
    s += __shfl_xor(s, 2);
    s += __shfl_xor(s, 4);
    s += __shfl_xor(s, 8);
    rden[reg] = 1.0f / s;
  }
  __syncthreads();
  // P A-frags once into registers, reused over 4 head-dim tiles
  short8 ap[9];
#pragma unroll
  for (int kc = 0; kc < 9; kc++)
    ap[kc] = *reinterpret_cast<const short8*>(&Pld[m16][kc * 32 + q4 * 8]);

  const int b = bh >> 4, h = bh & 15;
#pragma unroll
  for (int dt = 0; dt < 4; dt++) {
    f32x4 av = {0.f, 0.f, 0.f, 0.f};
    const unsigned short* vb = vTp + ((size_t)(bh * 64 + dt * 16 + m16)) * SP + i0 + q4 * 8;
#pragma unroll
    for (int kc = 0; kc < 9; kc++) {
      short8 bv = *reinterpret_cast<const short8*>(vb + kc * 32);
      av = __builtin_amdgcn_mfma_f32_16x16x32_bf16(ap[kc], bv, av, 0, 0, 0);
    }
#pragma unroll
    for (int reg = 0; reg < 4; reg++) {
      float val = av[reg] * rden[reg];
      int s = i0 + q4 * 4 + reg;
      int e = h * 64 + dt * 16 + m16;
      vals[((size_t)(b * 2048 + s)) * 1024 + e] = f2bf(val);
    }
  }
}

extern "C" void kernel_launch(void* const* d_in, const int* in_sizes, int n_in,
                              void* d_out, int out_size, void* d_ws, size_t ws_size,
                              hipStream_t stream) {
  const float* x    = (const float*)d_in[0];
  const int*   pm   = (const int*)d_in[1];
  const float* Wqkv = (const float*)d_in[2];
  const float* bqkv = (const float*)d_in[3];
  const float* Wo   = (const float*)d_in[4];
  const float* bo   = (const float*)d_in[5];
  float* out = (float*)d_out;
  char* ws = (char*)d_ws;

  unsigned short* xb    = (unsigned short*)(ws);                 //  8,388,608
  unsigned short* vals  = (unsigned short*)(ws);                 //  reuse (xb dead after gemm_qkv)
  unsigned short* Wqkvb = (unsigned short*)(ws +  8388608);      //  6,291,456
  unsigned short* Wob   = (unsigned short*)(ws + 14680064);      //  2,097,152
  unsigned short* qbuf  = (unsigned short*)(ws + 16777216);      //  8,388,608
  unsigned short* kbuf  = (unsigned short*)(ws + 25165824);      //  8,388,608
  unsigned short* vTp   = (unsigned short*)(ws + 33554432);      //  9,568,256 (ends 43,122,688)

  hipMemsetAsync(vTp, 0, (size_t)32 * 64 * SP * 2, stream);
  cvt_kernel<<<4096, 256, 0, stream>>>(x, xb, 1048576);
  cvt_kernel<<<3072, 256, 0, stream>>>(Wqkv, Wqkvb, 786432);
  cvt_kernel<<<1024, 256, 0, stream>>>(Wo, Wob, 262144);
  gemm_qkv<<<dim3(24, 32), 256, 0, stream>>>(xb, Wqkvb, bqkv, pm, qbuf, kbuf, vTp);
  attn_kernel<<<dim3(128, 32), 64, 0, stream>>>(qbuf, kbuf, vTp, vals);
  gemm_out<<<dim3(8, 32), 256, 0, stream>>>(vals, Wob, bo, out);
}

// Round 3
// 204.121 us; speedup vs baseline: 1.3015x; 1.0687x over previous
//
#include <hip/hip_runtime.h>
#include <stdint.h>

#define S_LEN 2048
#define EMBED 1024
#define HEADS 16
#define HD 64
#define M_ROWS 4096      // B*S
#define N_QKV 3072
#define KDIM 1024
#define SP 2336          // padded vT row length: 128 + 2048 + 160

typedef __attribute__((ext_vector_type(8))) short short8;
typedef __attribute__((ext_vector_type(4))) float f32x4;

__device__ __forceinline__ unsigned short f2bf(float f) {
  union { float f; uint32_t u; } c; c.f = f;
  uint32_t u = c.u;
  u += 0x7fffu + ((u >> 16) & 1u);  // round-to-nearest-even
  return (unsigned short)(u >> 16);
}

// async global->LDS, 16B per lane; lds base must be wave-uniform (HW adds lane*16)
__device__ __forceinline__ void gload_lds16(const unsigned short* g, unsigned short* l) {
  __builtin_amdgcn_global_load_lds(
      (const __attribute__((address_space(1))) void*)g,
      (__attribute__((address_space(3))) void*)l, 16, 0, 0);
}

// ---------------- fp32 -> bf16 conversion, 4 elems/thread ----------------
__global__ void cvt_kernel(const float* __restrict__ src, unsigned short* __restrict__ dst, int n4) {
  int i = blockIdx.x * blockDim.x + threadIdx.x;
  if (i >= n4) return;
  float4 f = reinterpret_cast<const float4*>(src)[i];
  ushort4 o;
  o.x = f2bf(f.x); o.y = f2bf(f.y); o.z = f2bf(f.z); o.w = f2bf(f.w);
  reinterpret_cast<ushort4*>(dst)[i] = o;
}

// ---------------- m97-style 128x128 GEMM body (QKV) ----------------
#define GEMM128_BODY(A_, B_)                                                          \
  __shared__ __align__(16) unsigned short As[128 * 32];                               \
  __shared__ __align__(16) unsigned short Bs[128 * 32];                               \
  const int t = threadIdx.x, wave = t >> 6, lane = t & 63;                            \
  const int m16 = lane & 15, q4 = lane >> 4;                                          \
  const int wm = wave >> 1, wn = wave & 1;                                            \
  const int nb = blockIdx.x, mb = blockIdx.y;                                         \
  const int srow = lane >> 2, scol = (lane & 3) << 3;                                 \
  const unsigned short* pA0 = A_ + (size_t)(mb * 128 + (wave * 2 + 0) * 16 + srow) * KDIM + scol; \
  const unsigned short* pA1 = A_ + (size_t)(mb * 128 + (wave * 2 + 1) * 16 + srow) * KDIM + scol; \
  const unsigned short* pB0 = B_ + (size_t)(nb * 128 + (wave * 2 + 0) * 16 + srow) * KDIM + scol; \
  const unsigned short* pB1 = B_ + (size_t)(nb * 128 + (wave * 2 + 1) * 16 + srow) * KDIM + scol; \
  unsigned short* lA0 = &As[(wave * 2 + 0) * 512];                                    \
  unsigned short* lA1 = &As[(wave * 2 + 1) * 512];                                    \
  unsigned short* lB0 = &Bs[(wave * 2 + 0) * 512];                                    \
  unsigned short* lB1 = &Bs[(wave * 2 + 1) * 512];                                    \
  f32x4 acc[4][4];                                                                    \
  _Pragma("unroll") for (int i_ = 0; i_ < 4; i_++)                                    \
    _Pragma("unroll") for (int j_ = 0; j_ < 4; j_++)                                  \
      acc[i_][j_] = (f32x4){0.f, 0.f, 0.f, 0.f};                                      \
  for (int kt = 0; kt < KDIM; kt += 32) {                                             \
    __syncthreads();                                                                  \
    gload_lds16(pA0 + kt, lA0);                                                       \
    gload_lds16(pA1 + kt, lA1);                                                       \
    gload_lds16(pB0 + kt, lB0);                                                       \
    gload_lds16(pB1 + kt, lB1);                                                       \
    __syncthreads();                                                                  \
    short8 af[4], bf[4];                                                              \
    _Pragma("unroll") for (int mt = 0; mt < 4; mt++)                                  \
      af[mt] = *reinterpret_cast<const short8*>(&As[(wm * 64 + mt * 16 + m16) * 32 + q4 * 8]); \
    _Pragma("unroll") for (int nt = 0; nt < 4; nt++)                                  \
      bf[nt] = *reinterpret_cast<const short8*>(&Bs[(wn * 64 + nt * 16 + m16) * 32 + q4 * 8]); \
    _Pragma("unroll") for (int mt = 0; mt < 4; mt++)                                  \
      _Pragma("unroll") for (int nt = 0; nt < 4; nt++)                                \
        acc[mt][nt] = __builtin_amdgcn_mfma_f32_16x16x32_bf16(af[mt], bf[nt], acc[mt][nt], 0, 0, 0); \
  }

// QKV projection + bias + padding mask + scatter to q/k/vT(padded)
__global__ __launch_bounds__(256) void gemm_qkv(
    const unsigned short* __restrict__ A, const unsigned short* __restrict__ Bm,
    const float* __restrict__ bias, const int* __restrict__ pm,
    unsigned short* __restrict__ qo, unsigned short* __restrict__ ko,
    unsigned short* __restrict__ vTp)
{
  GEMM128_BODY(A, Bm)
#pragma unroll
  for (int nt = 0; nt < 4; nt++) {
    int col = nb * 128 + wn * 64 + nt * 16 + m16;
    int h = col / 192, o = col % 192;
    float bv = bias[col];
#pragma unroll
    for (int mt = 0; mt < 4; mt++) {
#pragma unroll
      for (int reg = 0; reg < 4; reg++) {
        int row = mb * 128 + wm * 64 + mt * 16 + q4 * 4 + reg;
        float v = acc[mt][nt][reg] + bv;
        if (pm[row] != 0) v = 0.0f;
        unsigned short val = f2bf(v);
        int b = row >> 11, s = row & 2047;
        int bh = b * 16 + h;
        if (o < 64)       qo[((size_t)(bh * 2048 + s)) * 64 + o] = val;
        else if (o < 128) ko[((size_t)(bh * 2048 + s)) * 64 + (o - 64)] = val;
        else              vTp[((size_t)(bh * 64 + (o - 128))) * SP + 128 + s] = val;
      }
    }
  }
}

// ---------------- output projection: 64x128 tile, 512 blocks (2/CU) ----------------
__global__ __launch_bounds__(256) void gemm_out(
    const unsigned short* __restrict__ A, const unsigned short* __restrict__ Bm,
    const float* __restrict__ bias, float* __restrict__ out)
{
  __shared__ __align__(16) unsigned short As[64 * 32];    // 4 KB
  __shared__ __align__(16) unsigned short Bs[128 * 32];   // 8 KB
  const int t = threadIdx.x, wave = t >> 6, lane = t & 63;
  const int m16 = lane & 15, q4 = lane >> 4;
  const int wm = wave >> 1, wn = wave & 1;                // 2x2 waves: 32 rows x 64 cols each
  const int nb = blockIdx.x, mb = blockIdx.y;
  const int srow = lane >> 2, scol = (lane & 3) << 3;
  const unsigned short* pA = A + (size_t)(mb * 64 + wave * 16 + srow) * KDIM + scol;
  const unsigned short* pB0 = Bm + (size_t)(nb * 128 + wave * 32 + srow) * KDIM + scol;
  const unsigned short* pB1 = Bm + (size_t)(nb * 128 + wave * 32 + 16 + srow) * KDIM + scol;
  unsigned short* lA  = &As[(wave * 16) * 32];
  unsigned short* lB0 = &Bs[(wave * 32) * 32];
  unsigned short* lB1 = &Bs[(wave * 32 + 16) * 32];
  f32x4 acc[2][4];
#pragma unroll
  for (int i_ = 0; i_ < 2; i_++)
#pragma unroll
    for (int j_ = 0; j_ < 4; j_++) acc[i_][j_] = (f32x4){0.f, 0.f, 0.f, 0.f};
  for (int kt = 0; kt < KDIM; kt += 32) {
    __syncthreads();
    gload_lds16(pA + kt, lA);
    gload_lds16(pB0 + kt, lB0);
    gload_lds16(pB1 + kt, lB1);
    __syncthreads();
    short8 af[2], bf[4];
#pragma unroll
    for (int mt = 0; mt < 2; mt++)
      af[mt] = *reinterpret_cast<const short8*>(&As[(wm * 32 + mt * 16 + m16) * 32 + q4 * 8]);
#pragma unroll
    for (int nt = 0; nt < 4; nt++)
      bf[nt] = *reinterpret_cast<const short8*>(&Bs[(wn * 64 + nt * 16 + m16) * 32 + q4 * 8]);
#pragma unroll
    for (int mt = 0; mt < 2; mt++)
#pragma unroll
      for (int nt = 0; nt < 4; nt++)
        acc[mt][nt] = __builtin_amdgcn_mfma_f32_16x16x32_bf16(af[mt], bf[nt], acc[mt][nt], 0, 0, 0);
  }
#pragma unroll
  for (int nt = 0; nt < 4; nt++) {
    int col = nb * 128 + wn * 64 + nt * 16 + m16;
    float bv = bias[col];
#pragma unroll
    for (int mt = 0; mt < 2; mt++) {
#pragma unroll
      for (int reg = 0; reg < 4; reg++) {
        int row = mb * 64 + wm * 32 + mt * 16 + q4 * 4 + reg;
        out[(size_t)row * EMBED + col] = acc[mt][nt][reg] + bv;
      }
    }
  }
}

// ---------------- banded attention: 4 waves/block, bh-fastest grid ----------------
// block b: bh = b & 31 (XCD x owns bh%8==x -> K/V stay in one XCD's L2),
// wave w handles query tile qt = (b>>5)*4 + w.
__global__ __launch_bounds__(256) void attn_kernel(
    const unsigned short* __restrict__ q, const unsigned short* __restrict__ k,
    const unsigned short* __restrict__ vTp, unsigned short* __restrict__ vals)
{
  __shared__ __align__(16) unsigned short Pld[4][16][296]; // 37,888 B -> 4 blocks/CU
  const int bid = blockIdx.x;
  const int bh = bid & 31, qtg = bid >> 5;
  const int lane = threadIdx.x & 63, wave = threadIdx.x >> 6;
  const int qt = qtg * 4 + wave;
  const int i0 = qt * 16, w0 = i0 - 128;
  const int m16 = lane & 15, q4 = lane >> 4;

  const unsigned short* qb = q + ((size_t)(bh * 2048 + i0 + m16)) * 64 + q4 * 8;
  short8 aq0 = *reinterpret_cast<const short8*>(qb);
  short8 aq1 = *reinterpret_cast<const short8*>(qb + 32);

  // QK^T: 18 column tiles of 16 keys, accumulators stay in registers
  f32x4 sc[18];
#pragma unroll
  for (int ct = 0; ct < 18; ct++) {
    int js = w0 + ct * 16 + m16;
    int jc = js < 0 ? 0 : (js > 2047 ? 2047 : js);
    const unsigned short* kb = k + ((size_t)(bh * 2048 + jc)) * 64 + q4 * 8;
    short8 b0 = *reinterpret_cast<const short8*>(kb);
    short8 b1 = *reinterpret_cast<const short8*>(kb + 32);
    f32x4 a = {0.f, 0.f, 0.f, 0.f};
    a = __builtin_amdgcn_mfma_f32_16x16x32_bf16(aq0, b0, a, 0, 0, 0);
    a = __builtin_amdgcn_mfma_f32_16x16x32_bf16(aq1, b1, a, 0, 0, 0);
    sc[ct] = a;
  }
  // mask + scale in registers; per-row max over {18 regs} x {16 m16-lanes}
  float mx[4] = {-3.0e38f, -3.0e38f, -3.0e38f, -3.0e38f};
#pragma unroll
  for (int ct = 0; ct < 18; ct++) {
    int js = w0 + ct * 16 + m16;
#pragma unroll
    for (int reg = 0; reg < 4; reg++) {
      int i = i0 + q4 * 4 + reg;
      bool valid = (js >= 0) && (js < 2048) && (js >= i - 128) && (js <= i + 128);
      float v = valid ? sc[ct][reg] * 0.125f : -3.0e38f;
      sc[ct][reg] = v;
      mx[reg] = fmaxf(mx[reg], v);
    }
  }
#pragma unroll
  for (int reg = 0; reg < 4; reg++) {
    mx[reg] = fmaxf(mx[reg], __shfl_xor(mx[reg], 1));
    mx[reg] = fmaxf(mx[reg], __shfl_xor(mx[reg], 2));
    mx[reg] = fmaxf(mx[reg], __shfl_xor(mx[reg], 4));
    mx[reg] = fmaxf(mx[reg], __shfl_xor(mx[reg], 8));
  }
  float sum[4] = {0.f, 0.f, 0.f, 0.f};
#pragma unroll
  for (int ct = 0; ct < 18; ct++) {
#pragma unroll
    for (int reg = 0; reg < 4; reg++) {
      float e = __expf(sc[ct][reg] - mx[reg]);  // masked -> exp(-huge) = 0
      sum[reg] += e;
      Pld[wave][q4 * 4 + reg][ct * 16 + m16] = f2bf(e);
    }
  }
  float rden[4];
#pragma unroll
  for (int reg = 0; reg < 4; reg++) {
    float s = sum[reg];
    s += __shfl_xor(s, 1);
    s += __shfl_xor(s, 2);
    s += __shfl_xor(s, 4);
    s += __shfl_xor(s, 8);
    rden[reg] = 1.0f / s;
  }
  __syncthreads();
  // P A-frags once into registers, reused over 4 head-dim tiles
  short8 ap[9];
#pragma unroll
  for (int kc = 0; kc < 9; kc++)
    ap[kc] = *reinterpret_cast<const short8*>(&Pld[wave][m16][kc * 32 + q4 * 8]);

  const int b = bh >> 4, h = bh & 15;
#pragma unroll
  for (int dt = 0; dt < 4; dt++) {
    f32x4 av = {0.f, 0.f, 0.f, 0.f};
    const unsigned short* vb = vTp + ((size_t)(bh * 64 + dt * 16 + m16)) * SP + i0 + q4 * 8;
#pragma unroll
    for (int kc = 0; kc < 9; kc++) {
      short8 bv = *reinterpret_cast<const short8*>(vb + kc * 32);
      av = __builtin_amdgcn_mfma_f32_16x16x32_bf16(ap[kc], bv, av, 0, 0, 0);
    }
#pragma unroll
    for (int reg = 0; reg < 4; reg++) {
      float val = av[reg] * rden[reg];
      int s = i0 + q4 * 4 + reg;
      int e = h * 64 + dt * 16 + m16;
      vals[((size_t)(b * 2048 + s)) * 1024 + e] = f2bf(val);
    }
  }
}

extern "C" void kernel_launch(void* const* d_in, const int* in_sizes, int n_in,
                              void* d_out, int out_size, void* d_ws, size_t ws_size,
                              hipStream_t stream) {
  const float* x    = (const float*)d_in[0];
  const int*   pm   = (const int*)d_in[1];
  const float* Wqkv = (const float*)d_in[2];
  const float* bqkv = (const float*)d_in[3];
  const float* Wo   = (const float*)d_in[4];
  const float* bo   = (const float*)d_in[5];
  float* out = (float*)d_out;
  char* ws = (char*)d_ws;

  unsigned short* xb    = (unsigned short*)(ws);                 //  8,388,608
  unsigned short* vals  = (unsigned short*)(ws);                 //  reuse (xb dead after gemm_qkv)
  unsigned short* Wqkvb = (unsigned short*)(ws +  8388608);      //  6,291,456
  unsigned short* Wob   = (unsigned short*)(ws + 14680064);      //  2,097,152
  unsigned short* qbuf  = (unsigned short*)(ws + 16777216);      //  8,388,608
  unsigned short* kbuf  = (unsigned short*)(ws + 25165824);      //  8,388,608
  unsigned short* vTp   = (unsigned short*)(ws + 33554432);      //  9,568,256 (ends 43,122,688)

  hipMemsetAsync(vTp, 0, (size_t)32 * 64 * SP * 2, stream);
  cvt_kernel<<<4096, 256, 0, stream>>>(x, xb, 1048576);
  cvt_kernel<<<3072, 256, 0, stream>>>(Wqkv, Wqkvb, 786432);
  cvt_kernel<<<1024, 256, 0, stream>>>(Wo, Wob, 262144);
  gemm_qkv<<<dim3(24, 32), 256, 0, stream>>>(xb, Wqkvb, bqkv, pm, qbuf, kbuf, vTp);
  attn_kernel<<<1024, 256, 0, stream>>>(qbuf, kbuf, vTp, vals);
  gemm_out<<<dim3(8, 64), 256, 0, stream>>>(vals, Wob, bo, out);
}